// Round 1
// baseline (507.510 us; speedup 1.0000x reference)
//
#include <hip/hip_runtime.h>

typedef __attribute__((ext_vector_type(8))) short bf16x8;
typedef __attribute__((ext_vector_type(4))) float f32x4;
typedef __attribute__((ext_vector_type(8))) unsigned short u16x8;
typedef unsigned short u16;

#define GLOBAL_AS __attribute__((address_space(1)))
#define LDS_AS __attribute__((address_space(3)))

#define S_ 2048
#define SCALE_ 0.08838834764831845f

static __device__ __forceinline__ u16 f2bf(float f) {
  unsigned u = __builtin_bit_cast(unsigned, f);
  u += 0x7fffu + ((u >> 16) & 1u);
  return (u16)(u >> 16);
}
static __device__ __forceinline__ float bf2f(u16 h) {
  return __builtin_bit_cast(float, ((unsigned)h) << 16);
}

// ---------------- f32 -> bf16 convert ----------------
__global__ __launch_bounds__(256) void cvt_bf16(const float* __restrict__ src,
                                                u16* __restrict__ dst, long n) {
  long i = ((long)blockIdx.x * 256 + threadIdx.x) * 8;
  if (i >= n) return;
  f32x4 a = *(const f32x4*)(src + i);
  f32x4 b = *(const f32x4*)(src + i + 4);
  u16x8 o;
  o[0] = f2bf(a[0]); o[1] = f2bf(a[1]); o[2] = f2bf(a[2]); o[3] = f2bf(a[3]);
  o[4] = f2bf(b[0]); o[5] = f2bf(b[1]); o[6] = f2bf(b[2]); o[7] = f2bf(b[3]);
  *(u16x8*)(dst + i) = o;
}

// ---------------- GEMM: C[m][n] = sum_k A[m][k] * Bw[n][k] ----------------
// m97 structure: 128x128 tile, BK=64, 4 waves (2x2), global_load_lds width 16.
template <bool BF16OUT>
__global__ __launch_bounds__(256)
void gemm_bt(const u16* __restrict__ A, const u16* __restrict__ Bw,
             void* __restrict__ Cp, int M, int N, int K) {
  __shared__ u16 As[128 * 64];
  __shared__ u16 Bs[128 * 64];
  const int tid = threadIdx.x;
  const int wave = tid >> 6, lane = tid & 63;
  const int fr = lane & 15, fg = lane >> 4;
  const int wm = (wave >> 1) * 64, wn = (wave & 1) * 64;
  const long rowA = (long)blockIdx.y * 128;
  const long rowB = (long)blockIdx.x * 128;

  f32x4 acc[4][4] = {};

  for (int k0 = 0; k0 < K; k0 += 64) {
    __syncthreads();
#pragma unroll
    for (int c = 0; c < 4; ++c) {
      const int base = (wave * 4 + c) * 1024;  // byte offset, wave-uniform
      const int off = base + lane * 16;        // this lane's linear bytes
      const int r = off >> 7;                  // 128 B per LDS row
      const int kc = (off & 127) >> 1;
      __builtin_amdgcn_global_load_lds(
          (GLOBAL_AS void*)(A + (rowA + r) * (long)K + k0 + kc),
          (LDS_AS void*)(As + (base >> 1)), 16, 0, 0);
      __builtin_amdgcn_global_load_lds(
          (GLOBAL_AS void*)(Bw + (rowB + r) * (long)K + k0 + kc),
          (LDS_AS void*)(Bs + (base >> 1)), 16, 0, 0);
    }
    __syncthreads();
#pragma unroll
    for (int ks = 0; ks < 2; ++ks) {
      bf16x8 af[4], bfr[4];
#pragma unroll
      for (int i = 0; i < 4; ++i) {
        af[i]  = *(const bf16x8*)&As[(wm + i * 16 + fr) * 64 + ks * 32 + fg * 8];
        bfr[i] = *(const bf16x8*)&Bs[(wn + i * 16 + fr) * 64 + ks * 32 + fg * 8];
      }
#pragma unroll
      for (int i = 0; i < 4; ++i)
#pragma unroll
        for (int j = 0; j < 4; ++j)
          acc[i][j] = __builtin_amdgcn_mfma_f32_16x16x32_bf16(af[i], bfr[j], acc[i][j], 0, 0, 0);
    }
  }
#pragma unroll
  for (int i = 0; i < 4; ++i)
#pragma unroll
    for (int j = 0; j < 4; ++j)
#pragma unroll
      for (int r = 0; r < 4; ++r) {
        const long row = rowA + wm + i * 16 + fg * 4 + r;
        const long col = rowB + wn + j * 16 + fr;
        if (BF16OUT) ((u16*)Cp)[row * N + col] = f2bf(acc[i][j][r]);
        else         ((float*)Cp)[row * N + col] = acc[i][j][r];
      }
}

// ---------------- RoPE + rearrange to [b][h][s][hd] ----------------
__global__ __launch_bounds__(256)
void rope_rearrange(const u16* __restrict__ QKV, const float* __restrict__ cosb,
                    const float* __restrict__ sinb, u16* __restrict__ Qr,
                    u16* __restrict__ Kr, u16* __restrict__ Vr) {
  const int m = blockIdx.x;            // b*2048 + s
  const int b = m >> 11, s = m & 2047;
  const int t = threadIdx.x;
  const u16* row = QKV + (long)m * 3072;
  const float* cp = cosb + (long)m * 128;
  const float* sp = sinb + (long)m * 128;
#pragma unroll
  for (int i = 0; i < 4; ++i) {        // Q: 16 heads x 64 pairs
    const int idx = i * 256 + t;
    const int h = idx >> 6, d = idx & 63;
    const float x1 = bf2f(row[h * 128 + d]);
    const float x2 = bf2f(row[h * 128 + d + 64]);
    const float c = cp[d], sv = sp[d];     // cos[d+64]==cos[d], sin likewise
    const long o = ((long)(b * 16 + h) * S_ + s) * 128 + d;
    Qr[o] = f2bf(x1 * c - x2 * sv);
    Qr[o + 64] = f2bf(x2 * c + x1 * sv);
  }
  {                                     // K: 4 heads x 64 pairs
    const int h = t >> 6, d = t & 63;
    const float x1 = bf2f(row[2048 + h * 128 + d]);
    const float x2 = bf2f(row[2048 + h * 128 + d + 64]);
    const float c = cp[d], sv = sp[d];
    const long o = ((long)(b * 4 + h) * S_ + s) * 128 + d;
    Kr[o] = f2bf(x1 * c - x2 * sv);
    Kr[o + 64] = f2bf(x2 * c + x1 * sv);
  }
#pragma unroll
  for (int i = 0; i < 2; ++i) {         // V copy
    const int idx = i * 256 + t;
    const int h = idx >> 7, d = idx & 127;
    const long o = ((long)(b * 4 + h) * S_ + s) * 128 + d;
    Vr[o] = row[2560 + idx];
  }
}

// ---------------- causal GQA flash attention ----------------
#define QBLK 128
#define KVBLK 32
__global__ __launch_bounds__(256)
void attn_fwd(const u16* __restrict__ Qr, const u16* __restrict__ Kr,
              const u16* __restrict__ Vr, u16* __restrict__ Att) {
  __shared__ u16 Ks[KVBLK * 128];     // [kv][hd]
  __shared__ u16 Vt[128 * KVBLK];     // [hd][kv]
  __shared__ u16 Ps[4][32 * KVBLK];   // per-wave P

  const int bh = blockIdx.y;
  const int b = bh >> 4, h = bh & 15;
  const int kh = h >> 2;               // GQA: 4 q-heads per kv-head
  const int q0 = blockIdx.x * QBLK;
  const int tid = threadIdx.x, wave = tid >> 6, lane = tid & 63;
  const int fr = lane & 15, fg = lane >> 4;
  const int wq = wave * 32;

  const u16* Qb = Qr + (long)(b * 16 + h) * S_ * 128;
  const u16* Kb = Kr + (long)(b * 4 + kh) * S_ * 128;
  const u16* Vb = Vr + (long)(b * 4 + kh) * S_ * 128;

  // Q hoisted to registers: rows wq + mi*16 + fr, k = ks*32 + fg*8 + 0..7
  bf16x8 qf[2][4];
#pragma unroll
  for (int mi = 0; mi < 2; ++mi)
#pragma unroll
    for (int ks = 0; ks < 4; ++ks)
      qf[mi][ks] = *(const bf16x8*)&Qb[(long)(q0 + wq + mi * 16 + fr) * 128 + ks * 32 + fg * 8];

  f32x4 acc[2][8] = {};
  float m_run[2][4], l_run[2][4];
#pragma unroll
  for (int mi = 0; mi < 2; ++mi)
#pragma unroll
    for (int r = 0; r < 4; ++r) { m_run[mi][r] = -1e30f; l_run[mi][r] = 0.f; }

  const int kv_end = q0 + QBLK;
  for (int kv0 = 0; kv0 < kv_end; kv0 += KVBLK) {
    __syncthreads();
    // stage K tile (linear -> global_load_lds)
#pragma unroll
    for (int c = 0; c < 2; ++c) {
      const int base = (wave * 2 + c) * 1024;
      const int off = base + lane * 16;
      const int r = off >> 8;            // 256 B per row
      const int col = (off & 255) >> 1;
      __builtin_amdgcn_global_load_lds(
          (GLOBAL_AS void*)(Kb + (long)(kv0 + r) * 128 + col),
          (LDS_AS void*)(Ks + (base >> 1)), 16, 0, 0);
    }
    // stage V transposed via registers
#pragma unroll
    for (int c = 0; c < 2; ++c) {
      const int chunk = c * 256 + tid;
      const int kv = chunk >> 4;
      const int hd0 = (chunk & 15) * 8;
      bf16x8 v = *(const bf16x8*)&Vb[(long)(kv0 + kv) * 128 + hd0];
#pragma unroll
      for (int j = 0; j < 8; ++j)
        Vt[(hd0 + j) * KVBLK + kv] = (u16)v[j];
    }
    __syncthreads();

    // S = Q K^T
    f32x4 sf[2][2] = {};
#pragma unroll
    for (int ks = 0; ks < 4; ++ks) {
      bf16x8 kf[2];
#pragma unroll
      for (int ni = 0; ni < 2; ++ni)
        kf[ni] = *(const bf16x8*)&Ks[(ni * 16 + fr) * 128 + ks * 32 + fg * 8];
#pragma unroll
      for (int mi = 0; mi < 2; ++mi)
#pragma unroll
        for (int ni = 0; ni < 2; ++ni)
          sf[mi][ni] = __builtin_amdgcn_mfma_f32_16x16x32_bf16(qf[mi][ks], kf[ni], sf[mi][ni], 0, 0, 0);
    }

    // wave-parallel online softmax (rows = fg*4+r, cols across 16 lanes)
    float p[2][2][4];
#pragma unroll
    for (int mi = 0; mi < 2; ++mi) {
#pragma unroll
      for (int r = 0; r < 4; ++r) {
        const int qrow = q0 + wq + mi * 16 + fg * 4 + r;
        float mx = -1e30f;
#pragma unroll
        for (int ni = 0; ni < 2; ++ni) {
          const int kvg = kv0 + ni * 16 + fr;
          float v = sf[mi][ni][r] * SCALE_;
          if (kvg > qrow) v = -1e30f;    // causal
          p[mi][ni][r] = v;
          mx = fmaxf(mx, v);
        }
        mx = fmaxf(mx, __shfl_xor(mx, 1));
        mx = fmaxf(mx, __shfl_xor(mx, 2));
        mx = fmaxf(mx, __shfl_xor(mx, 4));
        mx = fmaxf(mx, __shfl_xor(mx, 8));
        const float mnew = fmaxf(m_run[mi][r], mx);
        const float sc = __expf(m_run[mi][r] - mnew);
#pragma unroll
        for (int nj = 0; nj < 8; ++nj) acc[mi][nj][r] *= sc;
        float rs = 0.f;
#pragma unroll
        for (int ni = 0; ni < 2; ++ni) {
          const float e = __expf(p[mi][ni][r] - mnew);
          p[mi][ni][r] = e;
          rs += e;
        }
        rs += __shfl_xor(rs, 1);
        rs += __shfl_xor(rs, 2);
        rs += __shfl_xor(rs, 4);
        rs += __shfl_xor(rs, 8);
        l_run[mi][r] = l_run[mi][r] * sc + rs;
        m_run[mi][r] = mnew;
      }
    }

    // P -> LDS (C-layout) ; read back in A-fragment layout
#pragma unroll
    for (int mi = 0; mi < 2; ++mi)
#pragma unroll
      for (int ni = 0; ni < 2; ++ni)
#pragma unroll
        for (int r = 0; r < 4; ++r)
          Ps[wave][(mi * 16 + fg * 4 + r) * KVBLK + ni * 16 + fr] = f2bf(p[mi][ni][r]);

    bf16x8 pf[2];
#pragma unroll
    for (int mi = 0; mi < 2; ++mi)
      pf[mi] = *(const bf16x8*)&Ps[wave][(mi * 16 + fr) * KVBLK + fg * 8];
#pragma unroll
    for (int nj = 0; nj < 8; ++nj) {
      bf16x8 vf = *(const bf16x8*)&Vt[(nj * 16 + fr) * KVBLK + fg * 8];
#pragma unroll
      for (int mi = 0; mi < 2; ++mi)
        acc[mi][nj] = __builtin_amdgcn_mfma_f32_16x16x32_bf16(pf[mi], vf, acc[mi][nj], 0, 0, 0);
    }
  }

  // epilogue: normalize and store [b][s][h*128+hd]
#pragma unroll
  for (int mi = 0; mi < 2; ++mi)
#pragma unroll
    for (int r = 0; r < 4; ++r) {
      const float inv = 1.0f / l_run[mi][r];
      const int qrow = q0 + wq + mi * 16 + fg * 4 + r;
      const long orow = ((long)b * S_ + qrow) * 2048 + h * 128;
#pragma unroll
      for (int nj = 0; nj < 8; ++nj)
        Att[orow + nj * 16 + fr] = f2bf(acc[mi][nj][r] * inv);
    }
}

extern "C" void kernel_launch(void* const* d_in, const int* in_sizes, int n_in,
                              void* d_out, int out_size, void* d_ws, size_t ws_size,
                              hipStream_t stream) {
  const float* hidden = (const float*)d_in[0];
  const float* cosb = (const float*)d_in[1];
  const float* sinb = (const float*)d_in[2];
  // d_in[3] = attn_mask: pure causal, implemented analytically
  const float* wq = (const float*)d_in[4];
  const float* wk = (const float*)d_in[5];
  const float* wv = (const float*)d_in[6];
  const float* wo = (const float*)d_in[7];
  float* out = (float*)d_out;

  u16* Xbf  = (u16*)d_ws;                 // 8,388,608  (X bf16)
  u16* Wqkv = Xbf + 8388608;              // 6,291,456  (wq|wk|wv rows)
  u16* Wo   = Wqkv + 6291456;             // 4,194,304
  u16* QKV  = Wo + 4194304;               // 12,582,912
  u16* Qr   = QKV + 12582912;             // 8,388,608
  u16* Kr   = Qr + 8388608;               // 2,097,152
  u16* Vr   = Kr + 2097152;               // 2,097,152
  u16* Att  = Xbf;                        // reuse X region after GEMM1
  if (ws_size < (size_t)44040192 * 2) return;

  cvt_bf16<<<dim3(4096), dim3(256), 0, stream>>>(hidden, Xbf, (long)8388608);
  cvt_bf16<<<dim3(2048), dim3(256), 0, stream>>>(wq, Wqkv, (long)4194304);
  cvt_bf16<<<dim3(512),  dim3(256), 0, stream>>>(wk, Wqkv + 4194304, (long)1048576);
  cvt_bf16<<<dim3(512),  dim3(256), 0, stream>>>(wv, Wqkv + 5242880, (long)1048576);
  cvt_bf16<<<dim3(2048), dim3(256), 0, stream>>>(wo, Wo, (long)4194304);

  gemm_bt<true><<<dim3(24, 32), dim3(256), 0, stream>>>(Xbf, Wqkv, (void*)QKV, 4096, 3072, 2048);
  rope_rearrange<<<dim3(4096), dim3(256), 0, stream>>>(QKV, cosb, sinb, Qr, Kr, Vr);
  attn_fwd<<<dim3(16, 32), dim3(256), 0, stream>>>(Qr, Kr, Vr, Att);
  gemm_bt<false><<<dim3(16, 32), dim3(256), 0, stream>>>(Att, Wo, (void*)out, 4096, 2048, 2048);
}

// Round 2
// 268.027 us; speedup vs baseline: 1.8935x; 1.8935x over previous
//
#include <hip/hip_runtime.h>

typedef __attribute__((ext_vector_type(8))) short bf16x8;
typedef __attribute__((ext_vector_type(4))) float f32x4;
typedef __attribute__((ext_vector_type(8))) unsigned short u16x8;
typedef unsigned short u16;

#define GLOBAL_AS __attribute__((address_space(1)))
#define LDS_AS __attribute__((address_space(3)))

#define S_ 2048
#define SCALE_ 0.08838834764831845f

static __device__ __forceinline__ u16 f2bf(float f) {
  unsigned u = __builtin_bit_cast(unsigned, f);
  u += 0x7fffu + ((u >> 16) & 1u);
  return (u16)(u >> 16);
}
static __device__ __forceinline__ float bf2f(u16 h) {
  return __builtin_bit_cast(float, ((unsigned)h) << 16);
}

// ---------------- f32 -> bf16 convert ----------------
__global__ __launch_bounds__(256) void cvt_bf16(const float* __restrict__ src,
                                                u16* __restrict__ dst, long n) {
  long i = ((long)blockIdx.x * 256 + threadIdx.x) * 8;
  if (i >= n) return;
  f32x4 a = *(const f32x4*)(src + i);
  f32x4 b = *(const f32x4*)(src + i + 4);
  u16x8 o;
  o[0] = f2bf(a[0]); o[1] = f2bf(a[1]); o[2] = f2bf(a[2]); o[3] = f2bf(a[3]);
  o[4] = f2bf(b[0]); o[5] = f2bf(b[1]); o[6] = f2bf(b[2]); o[7] = f2bf(b[3]);
  *(u16x8*)(dst + i) = o;
}

// ---------------- GEMM: C[m][n] = sum_k A[m][k] * Bw[n][k] ----------------
template <bool BF16OUT>
__global__ __launch_bounds__(256)
void gemm_bt(const u16* __restrict__ A, const u16* __restrict__ Bw,
             void* __restrict__ Cp, int M, int N, int K) {
  __shared__ u16 As[128 * 64];
  __shared__ u16 Bs[128 * 64];
  const int tid = threadIdx.x;
  const int wave = tid >> 6, lane = tid & 63;
  const int fr = lane & 15, fg = lane >> 4;
  const int wm = (wave >> 1) * 64, wn = (wave & 1) * 64;
  const long rowA = (long)blockIdx.y * 128;
  const long rowB = (long)blockIdx.x * 128;

  f32x4 acc[4][4] = {};

  for (int k0 = 0; k0 < K; k0 += 64) {
    __syncthreads();
#pragma unroll
    for (int c = 0; c < 4; ++c) {
      const int base = (wave * 4 + c) * 1024;  // byte offset, wave-uniform
      const int off = base + lane * 16;
      const int r = off >> 7;
      const int kc = (off & 127) >> 1;
      __builtin_amdgcn_global_load_lds(
          (GLOBAL_AS void*)(A + (rowA + r) * (long)K + k0 + kc),
          (LDS_AS void*)(As + (base >> 1)), 16, 0, 0);
      __builtin_amdgcn_global_load_lds(
          (GLOBAL_AS void*)(Bw + (rowB + r) * (long)K + k0 + kc),
          (LDS_AS void*)(Bs + (base >> 1)), 16, 0, 0);
    }
    __syncthreads();
#pragma unroll
    for (int ks = 0; ks < 2; ++ks) {
      bf16x8 af[4], bfr[4];
#pragma unroll
      for (int i = 0; i < 4; ++i) {
        af[i]  = *(const bf16x8*)&As[(wm + i * 16 + fr) * 64 + ks * 32 + fg * 8];
        bfr[i] = *(const bf16x8*)&Bs[(wn + i * 16 + fr) * 64 + ks * 32 + fg * 8];
      }
#pragma unroll
      for (int i = 0; i < 4; ++i)
#pragma unroll
        for (int j = 0; j < 4; ++j)
          acc[i][j] = __builtin_amdgcn_mfma_f32_16x16x32_bf16(af[i], bfr[j], acc[i][j], 0, 0, 0);
    }
  }
#pragma unroll
  for (int i = 0; i < 4; ++i)
#pragma unroll
    for (int j = 0; j < 4; ++j)
#pragma unroll
      for (int r = 0; r < 4; ++r) {
        const long row = rowA + wm + i * 16 + fg * 4 + r;
        const long col = rowB + wn + j * 16 + fr;
        if (BF16OUT) ((u16*)Cp)[row * N + col] = f2bf(acc[i][j][r]);
        else         ((float*)Cp)[row * N + col] = acc[i][j][r];
      }
}

// ---------------- RoPE + rearrange Q,K to [bh][s][hd] ----------------
__global__ __launch_bounds__(256)
void rope_rearrange(const u16* __restrict__ QKV, const float* __restrict__ cosb,
                    const float* __restrict__ sinb, u16* __restrict__ Qr,
                    u16* __restrict__ Kr) {
  const int m = blockIdx.x;            // b*2048 + s
  const int b = m >> 11, s = m & 2047;
  const int t = threadIdx.x;
  const u16* row = QKV + (long)m * 3072;
  const float* cp = cosb + (long)m * 128;
  const float* sp = sinb + (long)m * 128;
#pragma unroll
  for (int i = 0; i < 4; ++i) {        // Q: 16 heads x 64 pairs
    const int idx = i * 256 + t;
    const int h = idx >> 6, d = idx & 63;
    const float x1 = bf2f(row[h * 128 + d]);
    const float x2 = bf2f(row[h * 128 + d + 64]);
    const float c = cp[d], sv = sp[d];
    const long o = ((long)(b * 16 + h) * S_ + s) * 128 + d;
    Qr[o] = f2bf(x1 * c - x2 * sv);
    Qr[o + 64] = f2bf(x2 * c + x1 * sv);
  }
  {                                     // K: 4 heads x 64 pairs
    const int h = t >> 6, d = t & 63;
    const float x1 = bf2f(row[2048 + h * 128 + d]);
    const float x2 = bf2f(row[2048 + h * 128 + d + 64]);
    const float c = cp[d], sv = sp[d];
    const long o = ((long)(b * 4 + h) * S_ + s) * 128 + d;
    Kr[o] = f2bf(x1 * c - x2 * sv);
    Kr[o + 64] = f2bf(x2 * c + x1 * sv);
  }
}

// ---------------- V transpose: QKV[b][s][2560+kh*128+d] -> Vt[b][kh][d][s] ----
__global__ __launch_bounds__(256)
void transpose_v(const u16* __restrict__ QKV, u16* __restrict__ Vt) {
  __shared__ u16 t[32][33];
  const int s0 = blockIdx.x * 32, d0 = blockIdx.y * 32;
  const int bk = blockIdx.z;
  const int b = bk >> 2, kh = bk & 3;
  const int tx = threadIdx.x & 31, ty = threadIdx.x >> 5;
  const u16* src = QKV + 2560 + (long)kh * 128;
#pragma unroll
  for (int i = 0; i < 4; ++i) {
    const int sl = ty + i * 8;
    t[sl][tx] = src[(long)(b * S_ + s0 + sl) * 3072 + d0 + tx];
  }
  __syncthreads();
  u16* dst = Vt + (long)(b * 4 + kh) * 128 * S_;
#pragma unroll
  for (int i = 0; i < 4; ++i) {
    const int dl = ty + i * 8;
    dst[(long)(d0 + dl) * S_ + s0 + tx] = t[tx][dl];
  }
}

// ---------------- causal GQA flash attention ----------------
// QBLK=64, KVBLK=64, 4 waves x 16 q-rows. Block handles q-tile pair {bx, 31-bx}
// (uniform 33 KV-tiles/block). K/V/P LDS XOR-swizzled (chunk ^= row&7).
#define KVBLK 64
__global__ __launch_bounds__(256)
void attn_fwd(const u16* __restrict__ Qr, const u16* __restrict__ Kr,
              const u16* __restrict__ Vt, u16* __restrict__ Att) {
  __shared__ u16 Ks[KVBLK * 128];      // swizzled [kv][d]
  __shared__ u16 Vs[128 * KVBLK];      // swizzled [d][kv]
  __shared__ u16 Ps[4][16 * KVBLK];    // swizzled per-wave [q][kv]

  const int bh = blockIdx.y;
  const int b = bh >> 4, h = bh & 15;
  const int kh = h >> 2;
  const int tid = threadIdx.x, wave = tid >> 6, lane = tid & 63;
  const int fr = lane & 15, fg = lane >> 4;
  const int f7 = fr & 7;

  const u16* Qb = Qr + (long)(b * 16 + h) * S_ * 128;
  const u16* Kb = Kr + (long)(b * 4 + kh) * S_ * 128;
  const u16* Vg = Vt + (long)(b * 4 + kh) * 128 * (long)S_;
  u16* Pw = Ps[wave];

  for (int half = 0; half < 2; ++half) {
    const int qt = half ? (31 - blockIdx.x) : blockIdx.x;
    const int q0 = qt * 64;
    const int qbase = q0 + wave * 16;

    bf16x8 qf[4];
#pragma unroll
    for (int ks = 0; ks < 4; ++ks)
      qf[ks] = *(const bf16x8*)&Qb[(long)(qbase + fr) * 128 + ks * 32 + fg * 8];

    f32x4 acc[8] = {};
    float m_run[4], l_run[4];
#pragma unroll
    for (int r = 0; r < 4; ++r) { m_run[r] = -1e30f; l_run[r] = 0.f; }

    const int ntiles = qt + 1;
    for (int t = 0; t < ntiles; ++t) {
      const int kv0 = t * KVBLK;
      __syncthreads();
#pragma unroll
      for (int c = 0; c < 4; ++c) {
        const int slab = wave * 4 + c;          // 16 slabs x 1KB
        const int offu = slab * 512 + lane * 8; // this lane's linear u16 offset
        const int kvl = offu >> 7;              // K: 128 u16 per row
        const int kc = ((offu >> 3) & 15) ^ (kvl & 7);
        __builtin_amdgcn_global_load_lds(
            (GLOBAL_AS void*)(Kb + (long)(kv0 + kvl) * 128 + kc * 8),
            (LDS_AS void*)(Ks + slab * 512), 16, 0, 0);
        const int dr = offu >> 6;               // V: 64 u16 per row
        const int vc = ((offu >> 3) & 7) ^ (dr & 7);
        __builtin_amdgcn_global_load_lds(
            (GLOBAL_AS void*)(Vg + (long)dr * S_ + kv0 + vc * 8),
            (LDS_AS void*)(Vs + slab * 512), 16, 0, 0);
      }
      __syncthreads();

      // ---- S = Q K^T ----
      f32x4 sf[4] = {};
#pragma unroll
      for (int ks = 0; ks < 4; ++ks) {
        bf16x8 kf[4];
#pragma unroll
        for (int ni = 0; ni < 4; ++ni)
          kf[ni] = *(const bf16x8*)&Ks[(ni * 16 + fr) * 128 + (((ks * 4 + fg) ^ f7) << 3)];
        __builtin_amdgcn_s_setprio(1);
#pragma unroll
        for (int ni = 0; ni < 4; ++ni)
          sf[ni] = __builtin_amdgcn_mfma_f32_16x16x32_bf16(qf[ks], kf[ni], sf[ni], 0, 0, 0);
        __builtin_amdgcn_s_setprio(0);
      }

      // ---- online softmax (defer-max, threshold 8) ----
      float pr[4][4];
      float mx[4];
#pragma unroll
      for (int r = 0; r < 4; ++r) mx[r] = -3.0e38f;
#pragma unroll
      for (int ni = 0; ni < 4; ++ni) {
        const int kvg = kv0 + ni * 16 + fr;
#pragma unroll
        for (int r = 0; r < 4; ++r) {
          const int qrow = qbase + fg * 4 + r;
          float v = sf[ni][r] * SCALE_;
          if (kvg > qrow) v = -1e30f;   // causal
          pr[ni][r] = v;
          mx[r] = fmaxf(mx[r], v);
        }
      }
#pragma unroll
      for (int r = 0; r < 4; ++r) {
        mx[r] = fmaxf(mx[r], __shfl_xor(mx[r], 1));
        mx[r] = fmaxf(mx[r], __shfl_xor(mx[r], 2));
        mx[r] = fmaxf(mx[r], __shfl_xor(mx[r], 4));
        mx[r] = fmaxf(mx[r], __shfl_xor(mx[r], 8));
      }
      bool need = false;
#pragma unroll
      for (int r = 0; r < 4; ++r) need = need || (mx[r] > m_run[r] + 8.0f);
      if (__any(need)) {
#pragma unroll
        for (int r = 0; r < 4; ++r) {
          const float mn = fmaxf(m_run[r], mx[r]);
          const float scq = __expf(m_run[r] - mn);
          l_run[r] *= scq;
          m_run[r] = mn;
#pragma unroll
          for (int nj = 0; nj < 8; ++nj) acc[nj][r] *= scq;
        }
      }
      float rs[4] = {0.f, 0.f, 0.f, 0.f};
#pragma unroll
      for (int ni = 0; ni < 4; ++ni) {
        const int col = ni * 16 + fr;
        const int chs = col >> 3, wi = col & 7;
#pragma unroll
        for (int r = 0; r < 4; ++r) {
          const float e = __expf(pr[ni][r] - m_run[r]);
          rs[r] += e;
          const int row = fg * 4 + r;
          Pw[row * 64 + (((chs ^ (row & 7)) << 3) | wi)] = f2bf(e);
        }
      }
#pragma unroll
      for (int r = 0; r < 4; ++r) {
        rs[r] += __shfl_xor(rs[r], 1);
        rs[r] += __shfl_xor(rs[r], 2);
        rs[r] += __shfl_xor(rs[r], 4);
        rs[r] += __shfl_xor(rs[r], 8);
        l_run[r] += rs[r];
      }

      // ---- O += P V ----
      bf16x8 pf[2];
#pragma unroll
      for (int ks2 = 0; ks2 < 2; ++ks2)
        pf[ks2] = *(const bf16x8*)&Pw[fr * 64 + (((ks2 * 4 + fg) ^ f7) << 3)];
      __builtin_amdgcn_s_setprio(1);
#pragma unroll
      for (int nj = 0; nj < 8; ++nj) {
#pragma unroll
        for (int ks2 = 0; ks2 < 2; ++ks2) {
          const bf16x8 vf = *(const bf16x8*)&Vs[(nj * 16 + fr) * 64 + (((ks2 * 4 + fg) ^ f7) << 3)];
          acc[nj] = __builtin_amdgcn_mfma_f32_16x16x32_bf16(pf[ks2], vf, acc[nj], 0, 0, 0);
        }
      }
      __builtin_amdgcn_s_setprio(0);
    }

    // ---- epilogue: normalize, store [b][s][h*128+d] ----
#pragma unroll
    for (int r = 0; r < 4; ++r) {
      const float inv = 1.0f / l_run[r];
      const long orow = ((long)b * S_ + qbase + fg * 4 + r) * 2048 + h * 128;
#pragma unroll
      for (int nj = 0; nj < 8; ++nj)
        Att[orow + nj * 16 + fr] = f2bf(acc[nj][r] * inv);
    }
  }
}

extern "C" void kernel_launch(void* const* d_in, const int* in_sizes, int n_in,
                              void* d_out, int out_size, void* d_ws, size_t ws_size,
                              hipStream_t stream) {
  const float* hidden = (const float*)d_in[0];
  const float* cosb = (const float*)d_in[1];
  const float* sinb = (const float*)d_in[2];
  // d_in[3] = attn_mask: pure causal, implemented analytically
  const float* wq = (const float*)d_in[4];
  const float* wk = (const float*)d_in[5];
  const float* wv = (const float*)d_in[6];
  const float* wo = (const float*)d_in[7];
  float* out = (float*)d_out;

  u16* Xbf  = (u16*)d_ws;                 // 8,388,608
  u16* Wqkv = Xbf + 8388608;              // 6,291,456
  u16* Wo   = Wqkv + 6291456;             // 4,194,304
  u16* QKV  = Wo + 4194304;               // 12,582,912
  u16* Qr   = QKV + 12582912;             // 8,388,608
  u16* Kr   = Qr + 8388608;               // 2,097,152
  u16* Vtp  = Kr + 2097152;               // 2,097,152  (V transposed [b][kh][d][s])
  u16* Att  = Xbf;                        // reuse X region after GEMM1
  if (ws_size < (size_t)44040192 * 2) return;

  cvt_bf16<<<dim3(4096), dim3(256), 0, stream>>>(hidden, Xbf, (long)8388608);
  cvt_bf16<<<dim3(2048), dim3(256), 0, stream>>>(wq, Wqkv, (long)4194304);
  cvt_bf16<<<dim3(512),  dim3(256), 0, stream>>>(wk, Wqkv + 4194304, (long)1048576);
  cvt_bf16<<<dim3(512),  dim3(256), 0, stream>>>(wv, Wqkv + 5242880, (long)1048576);
  cvt_bf16<<<dim3(2048), dim3(256), 0, stream>>>(wo, Wo, (long)4194304);

  gemm_bt<true><<<dim3(24, 32), dim3(256), 0, stream>>>(Xbf, Wqkv, (void*)QKV, 4096, 3072, 2048);
  rope_rearrange<<<dim3(4096), dim3(256), 0, stream>>>(QKV, cosb, sinb, Qr, Kr);
  transpose_v<<<dim3(64, 4, 8), dim3(256), 0, stream>>>(QKV, Vtp);
  attn_fwd<<<dim3(16, 32), dim3(256), 0, stream>>>(Qr, Kr, Vtp, Att);
  gemm_bt<false><<<dim3(16, 32), dim3(256), 0, stream>>>(Att, Wo, (void*)out, 4096, 2048, 2048);
}